// Round 1
// baseline (379.173 us; speedup 1.0000x reference)
//
#include <hip/hip_runtime.h>
#include <math.h>

#define BN 256
#define SN 196
#define RN 1024
#define HN 512

__device__ __forceinline__ float fast_tanh(float x) {
    // tanh(x) = 1 - 2/(exp(2x)+1); exact saturation at +/-inf
    float e = __expf(2.0f * x);
    return 1.0f - 2.0f * __builtin_amdgcn_rcpf(e + 1.0f);
}

// Single fused kernel: per-block GEMV (att_h) -> scores -> softmax -> pool.
// grid 256 (1 block/CU), 1024 threads (16 waves). Zero workspace.
// W (2 MB) is L2-resident per XCD; the GEMV's L2-bound window is overlapped
// with an HBM register-prefetch of each wave's first 4 p_att rows.
__global__ __launch_bounds__(1024) void k_all(
    const float* __restrict__ hidden, const float* __restrict__ w,
    const float* __restrict__ bias, const float* __restrict__ p_att,
    const float* __restrict__ in_w, const float* __restrict__ alpha_w,
    const float* __restrict__ att_feats,
    float* __restrict__ att_res, float* __restrict__ weight_out) {
    __shared__ float4 hid4[RN / 4];    // 4 KB hidden row
    __shared__ float att_h[HN];        // 2 KB
    __shared__ float sc[256];          // scores (196 used, rest -1e30)
    __shared__ float red[16 * 256];    // 16 KB pool partials
    const int b    = blockIdx.x;
    const int t    = threadIdx.x;
    const int wv   = t >> 6;
    const int lane = t & 63;

    if (t >= SN && t < 256) sc[t] = -1e30f;
    if (t < 256) hid4[t] = ((const float4*)(hidden + (size_t)b * RN))[t];
    __syncthreads();

    // Issue HBM prefetch of this wave's first 4 score-rows NOW; the fetch
    // overlaps phase A's L2-bound W reads (post-A barrier drains vmcnt).
    float4 pf0[4], pf1[4];
    float  pfw[4];
    {
        const float4* p4 = (const float4*)p_att;
#pragma unroll
        for (int j = 0; j < 4; ++j) {
            const int si = wv + 16 * j;           // <= 63 < SN always
            pfw[j] = in_w[b * SN + si];
            const size_t rb = (size_t)(b * SN + si) * (HN / 4);
            pf0[j] = p4[rb + lane];
            pf1[j] = p4[rb + lane + 64];
        }
    }

    // ---- phase A: att_h[h] = hidden[b,:] . w[h,:] + bias[h] ----
    // wave wv owns rows [wv*32, wv*32+32); coalesced 1 KB loads per row,
    // hidden held in 16 VGPRs, 64-lane shuffle reduce per row pair.
    {
        const float4 x0 = hid4[lane],       x1 = hid4[lane + 64],
                     x2 = hid4[lane + 128], x3 = hid4[lane + 192];
        const int hbase = wv * 32;
        for (int r = 0; r < 32; r += 2) {
            const float4* wa = (const float4*)(w + (size_t)(hbase + r) * RN);
            const float4* wb = (const float4*)(w + (size_t)(hbase + r + 1) * RN);
            float4 a0 = wa[lane], a1 = wa[lane + 64],
                   a2 = wa[lane + 128], a3 = wa[lane + 192];
            float4 c0 = wb[lane], c1 = wb[lane + 64],
                   c2 = wb[lane + 128], c3 = wb[lane + 192];
            float da0 = a0.x * x0.x, da1 = a1.x * x1.x;
            da0 = fmaf(a0.y, x0.y, da0); da1 = fmaf(a1.y, x1.y, da1);
            da0 = fmaf(a0.z, x0.z, da0); da1 = fmaf(a1.z, x1.z, da1);
            da0 = fmaf(a0.w, x0.w, da0); da1 = fmaf(a1.w, x1.w, da1);
            da0 = fmaf(a2.x, x2.x, da0); da1 = fmaf(a3.x, x3.x, da1);
            da0 = fmaf(a2.y, x2.y, da0); da1 = fmaf(a3.y, x3.y, da1);
            da0 = fmaf(a2.z, x2.z, da0); da1 = fmaf(a3.z, x3.z, da1);
            da0 = fmaf(a2.w, x2.w, da0); da1 = fmaf(a3.w, x3.w, da1);
            float db0 = c0.x * x0.x, db1 = c1.x * x1.x;
            db0 = fmaf(c0.y, x0.y, db0); db1 = fmaf(c1.y, x1.y, db1);
            db0 = fmaf(c0.z, x0.z, db0); db1 = fmaf(c1.z, x1.z, db1);
            db0 = fmaf(c0.w, x0.w, db0); db1 = fmaf(c1.w, x1.w, db1);
            db0 = fmaf(c2.x, x2.x, db0); db1 = fmaf(c3.x, x3.x, db1);
            db0 = fmaf(c2.y, x2.y, db0); db1 = fmaf(c3.y, x3.y, db1);
            db0 = fmaf(c2.z, x2.z, db0); db1 = fmaf(c3.z, x3.z, db1);
            db0 = fmaf(c2.w, x2.w, db0); db1 = fmaf(c3.w, x3.w, db1);
            float da = da0 + da1, db = db0 + db1;
#pragma unroll
            for (int off = 32; off; off >>= 1) {
                da += __shfl_xor(da, off, 64);
                db += __shfl_xor(db, off, 64);
            }
            if (lane == 0) {
                att_h[hbase + r]     = da + bias[hbase + r];
                att_h[hbase + r + 1] = db + bias[hbase + r + 1];
            }
        }
    }
    __syncthreads();

    // ---- phase B: scores[s] = sum_h tanh(iw*p + att_h) * alpha_w ----
    // (alpha_b dropped: softmax is shift-invariant)
    {
        const float4* a4 = (const float4*)alpha_w;
        const float4 aw0 = a4[lane], aw1 = a4[lane + 64];
        const float4 ah0 = *(const float4*)&att_h[lane * 4];
        const float4 ah1 = *(const float4*)&att_h[(lane + 64) * 4];
        // first 4 rows from prefetch registers
#pragma unroll
        for (int j = 0; j < 4; ++j) {
            const int si = wv + 16 * j;
            const float iw = pfw[j];
            float4 p0 = pf0[j], p1 = pf1[j];
            float sum;
            sum  = fast_tanh(fmaf(iw, p0.x, ah0.x)) * aw0.x;
            sum += fast_tanh(fmaf(iw, p0.y, ah0.y)) * aw0.y;
            sum += fast_tanh(fmaf(iw, p0.z, ah0.z)) * aw0.z;
            sum += fast_tanh(fmaf(iw, p0.w, ah0.w)) * aw0.w;
            sum += fast_tanh(fmaf(iw, p1.x, ah1.x)) * aw1.x;
            sum += fast_tanh(fmaf(iw, p1.y, ah1.y)) * aw1.y;
            sum += fast_tanh(fmaf(iw, p1.z, ah1.z)) * aw1.z;
            sum += fast_tanh(fmaf(iw, p1.w, ah1.w)) * aw1.w;
#pragma unroll
            for (int off = 32; off; off >>= 1) sum += __shfl_xor(sum, off, 64);
            if (lane == 0) sc[si] = sum;
        }
        // remaining rows streamed from HBM
        const float4* p4 = (const float4*)p_att;
        for (int si = wv + 64; si < SN; si += 16) {
            const float iw = in_w[b * SN + si];
            const size_t rb = (size_t)(b * SN + si) * (HN / 4);
            float4 p0 = p4[rb + lane], p1 = p4[rb + lane + 64];
            float sum;
            sum  = fast_tanh(fmaf(iw, p0.x, ah0.x)) * aw0.x;
            sum += fast_tanh(fmaf(iw, p0.y, ah0.y)) * aw0.y;
            sum += fast_tanh(fmaf(iw, p0.z, ah0.z)) * aw0.z;
            sum += fast_tanh(fmaf(iw, p0.w, ah0.w)) * aw0.w;
            sum += fast_tanh(fmaf(iw, p1.x, ah1.x)) * aw1.x;
            sum += fast_tanh(fmaf(iw, p1.y, ah1.y)) * aw1.y;
            sum += fast_tanh(fmaf(iw, p1.z, ah1.z)) * aw1.z;
            sum += fast_tanh(fmaf(iw, p1.w, ah1.w)) * aw1.w;
#pragma unroll
            for (int off = 32; off; off >>= 1) sum += __shfl_xor(sum, off, 64);
            if (lane == 0) sc[si] = sum;
        }
    }
    __syncthreads();

    // ---- phase C: softmax over 196 (wave 0 only) ----
    if (wv == 0) {
        float v0 = sc[lane], v1 = sc[lane + 64], v2 = sc[lane + 128], v3 = sc[lane + 192];
        float m = fmaxf(fmaxf(v0, v1), fmaxf(v2, v3));
#pragma unroll
        for (int off = 32; off; off >>= 1) m = fmaxf(m, __shfl_xor(m, off, 64));
        float e0 = __expf(v0 - m), e1 = __expf(v1 - m);
        float e2 = __expf(v2 - m), e3 = __expf(v3 - m);
        float s = e0 + e1 + e2 + e3;
#pragma unroll
        for (int off = 32; off; off >>= 1) s += __shfl_xor(s, off, 64);
        float inv = 1.0f / s;
        e0 *= inv; e1 *= inv; e2 *= inv; e3 *= inv;
        sc[lane] = e0; sc[lane + 64] = e1; sc[lane + 128] = e2; sc[lane + 192] = e3;
        float* wo = weight_out + (size_t)b * SN;
        wo[lane] = e0; wo[lane + 64] = e1; wo[lane + 128] = e2;
        if (lane + 192 < SN) wo[lane + 192] = e3;
    }
    __syncthreads();

    // ---- phase D: att_res[r] = sum_s weight[s] * att_feats[b,s,r] ----
    // wave -> (s-group g, r-quarter q); 49 s per wave, unroll 7
    {
        const int g = wv >> 2, q = wv & 3;
        const float* base = att_feats + (size_t)b * SN * RN + q * 256 + lane * 4;
        float4 acc = {0, 0, 0, 0};
        for (int i = 0; i < 49; i += 7) {
#pragma unroll
            for (int j = 0; j < 7; ++j) {
                int s = g + 4 * (i + j);
                float ws = sc[s];
                float4 v = *(const float4*)(base + (size_t)s * RN);
                acc.x = fmaf(ws, v.x, acc.x);
                acc.y = fmaf(ws, v.y, acc.y);
                acc.z = fmaf(ws, v.z, acc.z);
                acc.w = fmaf(ws, v.w, acc.w);
            }
        }
        *(float4*)&red[wv * 256 + lane * 4] = acc;
    }
    __syncthreads();
    {
        const int q2 = t >> 8, rr = t & 255;
        float r = red[q2 * 256 + rr] + red[(4 + q2) * 256 + rr]
                + red[(8 + q2) * 256 + rr] + red[(12 + q2) * 256 + rr];
        att_res[(size_t)b * RN + t] = r;
    }
}

extern "C" void kernel_launch(void* const* d_in, const int* in_sizes, int n_in,
                              void* d_out, int out_size, void* d_ws, size_t ws_size,
                              hipStream_t stream) {
    const float* att_feats   = (const float*)d_in[0];  // [B,S,R]
    const float* p_att_feats = (const float*)d_in[1];  // [B,S,H]
    const float* hidden      = (const float*)d_in[2];  // [B,R]
    const float* in_weights  = (const float*)d_in[3];  // [B,S]
    const float* h2att_w     = (const float*)d_in[4];  // [H,R]
    const float* h2att_b     = (const float*)d_in[5];  // [H]
    const float* alpha_w     = (const float*)d_in[6];  // [1,H]

    float* att_res = (float*)d_out;                    // [B,R]
    float* weight  = (float*)d_out + BN * RN;          // [B,S]
    (void)d_ws; (void)ws_size;                         // workspace unused

    k_all<<<BN, 1024, 0, stream>>>(hidden, h2att_w, h2att_b, p_att_feats,
                                   in_weights, alpha_w, att_feats, att_res, weight);
}

// Round 2
// 371.455 us; speedup vs baseline: 1.0208x; 1.0208x over previous
//
#include <hip/hip_runtime.h>
#include <math.h>

#define BN 256
#define SN 196
#define RN 1024
#define HN 512
#define KSPLIT 8
#define KCH 128   // per gemm block: two 64-wide sub-chunks, LDS reused
#define PSPLIT 8  // pool s-splits

__device__ __forceinline__ float fast_tanh(float x) {
    // tanh(x) = 1 - 2/(exp(2x)+1); exact saturation at +/-inf
    float e = __expf(2.0f * x);
    return 1.0f - 2.0f * __builtin_amdgcn_rcpf(e + 1.0f);
}

// ---------------- kernel 1: split-K GEMV partials (proven ~10us) ----------------
// partial[kc][b][h] = hidden[b, kc*128:(kc+1)*128] . w[h, kc*128:(kc+1)*128]
__global__ __launch_bounds__(256) void k_gemm_partial(
    const float* __restrict__ hidden, const float* __restrict__ w,
    float* __restrict__ partial) {
    __shared__ float At[64][64];
    __shared__ float Bt[64][64];
    const int t  = threadIdx.x;
    const int b0 = blockIdx.x * 64;
    const int h0 = blockIdx.y * 64;
    const int kc = blockIdx.z;

    const int th4 = (t & 15) * 4;
    const int tb4 = (t >> 4) * 4;
    float4 acc0 = {0,0,0,0}, acc1 = {0,0,0,0}, acc2 = {0,0,0,0}, acc3 = {0,0,0,0};

    for (int sub = 0; sub < 2; ++sub) {
        const int k0 = kc * KCH + sub * 64;
        {
            const int row = t >> 2, kq = (t & 3) * 16;
            const float* srcA = hidden + (size_t)(b0 + row) * RN + k0 + kq;
            const float* srcB = w      + (size_t)(h0 + row) * RN + k0 + kq;
#pragma unroll
            for (int j = 0; j < 4; ++j) {
                float4 v = *(const float4*)(srcA + j * 4);
                int k = kq + j * 4;
                At[k][row] = v.x; At[k+1][row] = v.y; At[k+2][row] = v.z; At[k+3][row] = v.w;
            }
#pragma unroll
            for (int j = 0; j < 4; ++j) {
                float4 v = *(const float4*)(srcB + j * 4);
                int k = kq + j * 4;
                Bt[k][row] = v.x; Bt[k+1][row] = v.y; Bt[k+2][row] = v.z; Bt[k+3][row] = v.w;
            }
        }
        __syncthreads();
#pragma unroll 8
        for (int k = 0; k < 64; ++k) {
            float4 a  = *(const float4*)&At[k][tb4];
            float4 bb = *(const float4*)&Bt[k][th4];
            acc0.x = fmaf(a.x, bb.x, acc0.x); acc0.y = fmaf(a.x, bb.y, acc0.y);
            acc0.z = fmaf(a.x, bb.z, acc0.z); acc0.w = fmaf(a.x, bb.w, acc0.w);
            acc1.x = fmaf(a.y, bb.x, acc1.x); acc1.y = fmaf(a.y, bb.y, acc1.y);
            acc1.z = fmaf(a.y, bb.z, acc1.z); acc1.w = fmaf(a.y, bb.w, acc1.w);
            acc2.x = fmaf(a.z, bb.x, acc2.x); acc2.y = fmaf(a.z, bb.y, acc2.y);
            acc2.z = fmaf(a.z, bb.z, acc2.z); acc2.w = fmaf(a.z, bb.w, acc2.w);
            acc3.x = fmaf(a.w, bb.x, acc3.x); acc3.y = fmaf(a.w, bb.y, acc3.y);
            acc3.z = fmaf(a.w, bb.z, acc3.z); acc3.w = fmaf(a.w, bb.w, acc3.w);
        }
        __syncthreads();
    }
    float* dst = partial + ((size_t)kc * BN + b0 + tb4) * HN + h0 + th4;
    *(float4*)(dst)          = acc0;
    *(float4*)(dst + HN)     = acc1;
    *(float4*)(dst + 2 * HN) = acc2;
    *(float4*)(dst + 3 * HN) = acc3;
}

// ---------------- kernel 2: reduce + scores + softmax ----------------
// 256 blocks x 1024 thr. 2 score-rows per loop iter -> 4 float4 loads in flight.
__global__ __launch_bounds__(1024) void k_scores(
    const float* __restrict__ partial, const float* __restrict__ bias,
    const float* __restrict__ p_att, const float* __restrict__ in_w,
    const float* __restrict__ alpha_w, float* __restrict__ weight_out) {
    __shared__ float att_h[HN];
    __shared__ float sc[256];
    const int b    = blockIdx.x;
    const int t    = threadIdx.x;
    const int wv   = t >> 6;
    const int lane = t & 63;

    if (t >= SN && t < 256) sc[t] = -1e30f;

    // att_h[h] = bias[h] + sum_kc partial[kc][b][h]
    if (t < 128) {
        float4 s = *(const float4*)(bias + t * 4);
        const float* p = partial + (size_t)b * HN + t * 4;
#pragma unroll
        for (int kc = 0; kc < KSPLIT; ++kc) {
            float4 v = *(const float4*)(p + (size_t)kc * BN * HN);
            s.x += v.x; s.y += v.y; s.z += v.z; s.w += v.w;
        }
        *(float4*)&att_h[t * 4] = s;
    }
    __syncthreads();

    // scores[s] = sum_h tanh(iw*p + att_h) * alpha_w  (alpha_b dropped:
    // softmax is shift-invariant). Two rows per iteration for ILP.
    {
        const float4* a4 = (const float4*)alpha_w;
        const float4 aw0 = a4[lane], aw1 = a4[lane + 64];
        const float4 ah0 = *(const float4*)&att_h[lane * 4];
        const float4 ah1 = *(const float4*)&att_h[(lane + 64) * 4];
        const float4* p4 = (const float4*)p_att;
        for (int si = wv; si < SN; si += 32) {
            const int  sj = si + 16;
            const bool h2 = (sj < SN);
            const float iw0 = in_w[b * SN + si];
            const float iw1 = h2 ? in_w[b * SN + sj] : 0.0f;
            const size_t r0 = (size_t)(b * SN + si) * (HN / 4);
            const size_t r1 = (size_t)(b * SN + (h2 ? sj : si)) * (HN / 4);
            float4 x00 = p4[r0 + lane], x01 = p4[r0 + lane + 64];
            float4 x10 = p4[r1 + lane], x11 = p4[r1 + lane + 64];
            float s0, s1;
            s0  = fast_tanh(fmaf(iw0, x00.x, ah0.x)) * aw0.x;
            s1  = fast_tanh(fmaf(iw1, x10.x, ah0.x)) * aw0.x;
            s0 += fast_tanh(fmaf(iw0, x00.y, ah0.y)) * aw0.y;
            s1 += fast_tanh(fmaf(iw1, x10.y, ah0.y)) * aw0.y;
            s0 += fast_tanh(fmaf(iw0, x00.z, ah0.z)) * aw0.z;
            s1 += fast_tanh(fmaf(iw1, x10.z, ah0.z)) * aw0.z;
            s0 += fast_tanh(fmaf(iw0, x00.w, ah0.w)) * aw0.w;
            s1 += fast_tanh(fmaf(iw1, x10.w, ah0.w)) * aw0.w;
            s0 += fast_tanh(fmaf(iw0, x01.x, ah1.x)) * aw1.x;
            s1 += fast_tanh(fmaf(iw1, x11.x, ah1.x)) * aw1.x;
            s0 += fast_tanh(fmaf(iw0, x01.y, ah1.y)) * aw1.y;
            s1 += fast_tanh(fmaf(iw1, x11.y, ah1.y)) * aw1.y;
            s0 += fast_tanh(fmaf(iw0, x01.z, ah1.z)) * aw1.z;
            s1 += fast_tanh(fmaf(iw1, x11.z, ah1.z)) * aw1.z;
            s0 += fast_tanh(fmaf(iw0, x01.w, ah1.w)) * aw1.w;
            s1 += fast_tanh(fmaf(iw1, x11.w, ah1.w)) * aw1.w;
#pragma unroll
            for (int off = 32; off; off >>= 1) {
                s0 += __shfl_xor(s0, off, 64);
                s1 += __shfl_xor(s1, off, 64);
            }
            if (lane == 0) {
                sc[si] = s0;
                if (h2) sc[sj] = s1;
            }
        }
    }
    __syncthreads();

    // softmax over 196 (wave 0 only) -> normalized weights to global
    if (wv == 0) {
        float v0 = sc[lane], v1 = sc[lane + 64], v2 = sc[lane + 128], v3 = sc[lane + 192];
        float m = fmaxf(fmaxf(v0, v1), fmaxf(v2, v3));
#pragma unroll
        for (int off = 32; off; off >>= 1) m = fmaxf(m, __shfl_xor(m, off, 64));
        float e0 = __expf(v0 - m), e1 = __expf(v1 - m);
        float e2 = __expf(v2 - m), e3 = __expf(v3 - m);
        float s = e0 + e1 + e2 + e3;
#pragma unroll
        for (int off = 32; off; off >>= 1) s += __shfl_xor(s, off, 64);
        float inv = 1.0f / s;
        e0 *= inv; e1 *= inv; e2 *= inv; e3 *= inv;
        float* wo = weight_out + (size_t)b * SN;
        wo[lane] = e0; wo[lane + 64] = e1; wo[lane + 128] = e2;
        if (lane + 192 < SN) wo[lane + 192] = e3;
    }
}

// ---------------- kernel 3: pool partials, 8-way s-split ----------------
// grid (BN, PSPLIT) x 256 thr -> 8 blocks/CU x 4 waves = 32 waves/CU (100% occ).
// wave q owns r-quarter q*256..q*256+255; block covers 24-25 s values.
__global__ __launch_bounds__(256) void k_pool(
    const float* __restrict__ weight, const float* __restrict__ att_feats,
    float* __restrict__ pool_part) {
    __shared__ float wsm[32];
    const int b  = blockIdx.x, sq = blockIdx.y;
    const int t  = threadIdx.x, q = t >> 6, lane = t & 63;
    const int base = sq * 24 + (sq < 4 ? sq : 4);   // splits: 25,25,25,25,24,24,24,24
    const int cnt  = 24 + (sq < 4 ? 1 : 0);
    if (t < cnt) wsm[t] = weight[b * SN + base + t];
    __syncthreads();

    const float* src = att_feats + (size_t)b * SN * RN + (size_t)base * RN
                     + q * 256 + lane * 4;
    float4 acc = {0, 0, 0, 0};
    int i = 0;
    for (; i + 5 <= cnt; i += 5) {
#pragma unroll
        for (int j = 0; j < 5; ++j) {
            float ws = wsm[i + j];
            float4 v = *(const float4*)(src + (size_t)(i + j) * RN);
            acc.x = fmaf(ws, v.x, acc.x);
            acc.y = fmaf(ws, v.y, acc.y);
            acc.z = fmaf(ws, v.z, acc.z);
            acc.w = fmaf(ws, v.w, acc.w);
        }
    }
#pragma unroll
    for (; i < cnt; ++i) {
        float ws = wsm[i];
        float4 v = *(const float4*)(src + (size_t)i * RN);
        acc.x = fmaf(ws, v.x, acc.x);
        acc.y = fmaf(ws, v.y, acc.y);
        acc.z = fmaf(ws, v.z, acc.z);
        acc.w = fmaf(ws, v.w, acc.w);
    }
    float* dst = pool_part + ((size_t)sq * BN + b) * RN + q * 256 + lane * 4;
    *(float4*)dst = acc;
}

// ---------------- kernel 4: deterministic 8-way partial reduce ----------------
__global__ __launch_bounds__(256) void k_reduce(
    const float* __restrict__ pool_part, float* __restrict__ att_res) {
    const int e = blockIdx.x * 256 + threadIdx.x;
    float s = 0.0f;
#pragma unroll
    for (int sq = 0; sq < PSPLIT; ++sq)
        s += pool_part[(size_t)sq * BN * RN + e];
    att_res[e] = s;
}

extern "C" void kernel_launch(void* const* d_in, const int* in_sizes, int n_in,
                              void* d_out, int out_size, void* d_ws, size_t ws_size,
                              hipStream_t stream) {
    const float* att_feats   = (const float*)d_in[0];  // [B,S,R]
    const float* p_att_feats = (const float*)d_in[1];  // [B,S,H]
    const float* hidden      = (const float*)d_in[2];  // [B,R]
    const float* in_weights  = (const float*)d_in[3];  // [B,S]
    const float* h2att_w     = (const float*)d_in[4];  // [H,R]
    const float* h2att_b     = (const float*)d_in[5];  // [H]
    const float* alpha_w     = (const float*)d_in[6];  // [1,H]

    float* att_res = (float*)d_out;                    // [B,R]
    float* weight  = (float*)d_out + BN * RN;          // [B,S]
    float* partial   = (float*)d_ws;                            // [KSPLIT,B,H] = 4 MB
    float* pool_part = (float*)d_ws + (size_t)KSPLIT * BN * HN; // [PSPLIT,B,R] = 8 MB

    k_gemm_partial<<<dim3(BN / 64, HN / 64, KSPLIT), 256, 0, stream>>>(
        hidden, h2att_w, partial);
    k_scores<<<BN, 1024, 0, stream>>>(partial, h2att_b, p_att_feats, in_weights,
                                      alpha_w, weight);
    k_pool<<<dim3(BN, PSPLIT), 256, 0, stream>>>(weight, att_feats, pool_part);
    k_reduce<<<(BN * RN) / 256, 256, 0, stream>>>(pool_part, att_res);
}